// Round 2
// baseline (8435.544 us; speedup 1.0000x reference)
//
#include <hip/hip_runtime.h>
#include <hip/hip_bf16.h>
#include <math.h>

#define BB 64
#define TT 128
#define VV 10000
#define EE 300
#define HH 1024
#define TM1 127

typedef __hip_bfloat16 bf16;
typedef __attribute__((ext_vector_type(8))) short s8v;   // 8 bf16 = 4 VGPRs (MFMA A/B frag)
typedef __attribute__((ext_vector_type(4))) float f4v;   // 4 fp32 (MFMA C/D frag)

// async global->LDS, 16B per lane; LDS dest is wave-uniform base + lane*16
__device__ __forceinline__ void async_copy16(const void* g, void* s) {
    __builtin_amdgcn_global_load_lds((const __attribute__((address_space(1))) void*)g,
                                     (__attribute__((address_space(3))) void*)s, 16, 0, 0);
}

// ---------------- zero ----------------
__global__ void zero_kernel(float* __restrict__ p, int n) {
    int i = blockIdx.x * blockDim.x + threadIdx.x;
    if (i < n) p[i] = 0.0f;
}

// ---------------- embedding gather -> bf16, padded [128*64][320] ----------------
__global__ void embed_kernel(const int* __restrict__ sent,
                             const float* __restrict__ wordvec,
                             bf16* __restrict__ X) {
    int bi = blockIdx.x;          // t*64+b, t in [0,128)
    int t = bi >> 6;
    int b = bi & 63;
    int w = (t < TM1) ? sent[b * TT + t] : 0;
    const float* src = wordvec + (long)w * EE;
    bf16* dst = X + (long)bi * 320;
    for (int e = threadIdx.x; e < 320; e += 64) {
        float v = (t < TM1 && e < EE) ? src[e] : 0.0f;
        dst[e] = __float2bfloat16(v);
    }
}

// ---------------- transpose+convert: src fp32 [K][N] -> dst bf16 [Nrows][Kpad] ----------------
__global__ void transpose_bf16_kernel(const float* __restrict__ src,
                                      bf16* __restrict__ dst,
                                      int K, int N, int Kpad) {
    __shared__ float tile[32][33];
    int n0 = blockIdx.x * 32, k0 = blockIdx.y * 32;
    int tid = threadIdx.x;
    {
        int tn = tid & 31, tk = tid >> 5;
        #pragma unroll
        for (int i = 0; i < 4; i++) {
            int k = tk + i * 8;
            float v = (k0 + k < K && n0 + tn < N) ? src[(long)(k0 + k) * N + n0 + tn] : 0.0f;
            tile[k][tn] = v;
        }
    }
    __syncthreads();
    {
        int wk = tid & 31, wn = tid >> 5;
        #pragma unroll
        for (int i = 0; i < 4; i++) {
            int n = wn + i * 8;
            dst[(long)(n0 + n) * Kpad + k0 + wk] = __float2bfloat16(tile[wk][n]);
        }
    }
}

// ---------------- fused LSTM step (MFMA), v2: one block owns ALL 64 batch rows ----------------
// Block (phase, j): 64 batch rows x 16 hidden cols (j*16..), all 4 gates.
// 1024 threads = 16 waves: wave = 4*m + g handles gate g, row-tile m (rows m*16..m*16+15).
// Weights for a j-slice are fetched exactly ONCE per step (was 4x).
// Combo grid: blocks 0..63 = phase B (j=bid), 64..127 = phase A (j=bid&63);
// A- and B-blocks of a given j land on XCD j%8 -> per-XCD weight set ~3.4MB, L2-resident.
__global__ __launch_bounds__(1024) void step_kernel(
    const bf16* __restrict__ X, int ta, int tb, int a_only,
    const bf16* __restrict__ h0_in, bf16* __restrict__ h0_out,
    const bf16* __restrict__ h1_in, bf16* __restrict__ h1_out,
    const bf16* __restrict__ wt_ih0, const bf16* __restrict__ wt_hh0,
    const bf16* __restrict__ wt_ih1, const bf16* __restrict__ wt_hh1,
    const float* __restrict__ b0, const float* __restrict__ b1,
    float* __restrict__ c0, float* __restrict__ c1,
    bf16* __restrict__ H1)
{
    __shared__ float gbuf[4][64][17];
    int bid = blockIdx.x;
    int isA, j;
    if (a_only) { isA = 1; j = bid; }
    else        { isA = (bid >= 64); j = bid & 63; }
    const int tid = threadIdx.x;
    const int wave = tid >> 6, g = wave & 3, m = wave >> 2;
    const int L = tid & 63, quad = L >> 4, l16 = L & 15;

    const int arow = m * 16 + l16;             // batch row this lane's A-frag covers
    const int wrow = g * HH + j * 16 + l16;    // transposed-weight row (output col)

    f4v acc0 = {0.f, 0.f, 0.f, 0.f};
    f4v acc1 = {0.f, 0.f, 0.f, 0.f};

    if (isA) {
        // segment 1: x(ta) @ w_ih0, K=320 (padded 300)
        const s8v* ax = (const s8v*)(X + ((long)(ta * 64 + arow)) * 320 + quad * 8);
        const s8v* bx = (const s8v*)(wt_ih0 + (long)wrow * 320 + quad * 8);
        #pragma unroll
        for (int k = 0; k < 10; k++) {
            if (k & 1) acc1 = __builtin_amdgcn_mfma_f32_16x16x32_bf16(ax[k*4], bx[k*4], acc1, 0, 0, 0);
            else       acc0 = __builtin_amdgcn_mfma_f32_16x16x32_bf16(ax[k*4], bx[k*4], acc0, 0, 0, 0);
        }
        // segment 2: h0 @ w_hh0, K=1024
        const s8v* ah = (const s8v*)(h0_in + (long)arow * HH + quad * 8);
        const s8v* bh = (const s8v*)(wt_hh0 + (long)wrow * HH + quad * 8);
        #pragma unroll 8
        for (int k = 0; k < 32; k++) {
            if (k & 1) acc1 = __builtin_amdgcn_mfma_f32_16x16x32_bf16(ah[k*4], bh[k*4], acc1, 0, 0, 0);
            else       acc0 = __builtin_amdgcn_mfma_f32_16x16x32_bf16(ah[k*4], bh[k*4], acc0, 0, 0, 0);
        }
    } else {
        // segment 1: h0(tb) @ w_ih1
        const s8v* a0 = (const s8v*)(h0_in + (long)arow * HH + quad * 8);
        const s8v* b0f = (const s8v*)(wt_ih1 + (long)wrow * HH + quad * 8);
        #pragma unroll 8
        for (int k = 0; k < 32; k++) {
            if (k & 1) acc1 = __builtin_amdgcn_mfma_f32_16x16x32_bf16(a0[k*4], b0f[k*4], acc1, 0, 0, 0);
            else       acc0 = __builtin_amdgcn_mfma_f32_16x16x32_bf16(a0[k*4], b0f[k*4], acc0, 0, 0, 0);
        }
        // segment 2: h1(tb-1) @ w_hh1
        const s8v* a1 = (const s8v*)(h1_in + (long)arow * HH + quad * 8);
        const s8v* b1f = (const s8v*)(wt_hh1 + (long)wrow * HH + quad * 8);
        #pragma unroll 8
        for (int k = 0; k < 32; k++) {
            if (k & 1) acc1 = __builtin_amdgcn_mfma_f32_16x16x32_bf16(a1[k*4], b1f[k*4], acc1, 0, 0, 0);
            else       acc0 = __builtin_amdgcn_mfma_f32_16x16x32_bf16(a1[k*4], b1f[k*4], acc0, 0, 0, 0);
        }
    }
    acc0 += acc1;

    // C/D layout: col=lane&15, row=quad*4+reg
    #pragma unroll
    for (int i = 0; i < 4; i++) gbuf[g][m * 16 + quad * 4 + i][l16] = acc0[i];
    __syncthreads();

    // elementwise LSTM update: 1024 threads -> one (row,col) each of the 64x16 tile
    {
        int row = tid >> 4, col = tid & 15;
        int hcol = j * 16 + col;
        const float* bias = isA ? b0 : b1;
        float gi = gbuf[0][row][col] + bias[hcol];
        float gf = gbuf[1][row][col] + bias[HH + hcol];
        float gg = gbuf[2][row][col] + bias[2 * HH + hcol];
        float go = gbuf[3][row][col] + bias[3 * HH + hcol];
        float* cst = isA ? c0 : c1;
        int idx = row * HH + hcol;
        float c = cst[idx];
        float si = 1.0f / (1.0f + expf(-gi));
        float sf = 1.0f / (1.0f + expf(-gf));
        float so = 1.0f / (1.0f + expf(-go));
        float cn = sf * c + si * tanhf(gg);
        float hn = so * tanhf(cn);
        cst[idx] = cn;
        bf16 hb = __float2bfloat16(hn);
        if (isA) h0_out[idx] = hb;
        else {
            h1_out[idx] = hb;
            H1[((long)row * TM1 + tb) * HH + hcol] = hb;
        }
    }
}

// ---------------- output GEMM (MFMA + LDS staging via global_load_lds) ----------------
// out = H1 @ w_out + b_out. Tile 128x128, BK=32, 4 waves 2x2, wave = 64x64 = 4x4 MFMA tiles.
// m97 structure: stage -> barrier -> 8 ds_read_b128 + 16 MFMA -> barrier.
__global__ __launch_bounds__(256) void out_gemm_mfma(
    const bf16* __restrict__ A, const bf16* __restrict__ Wt,
    const float* __restrict__ bias, float* __restrict__ out)
{
    __shared__ __align__(16) bf16 As[128 * 32];
    __shared__ __align__(16) bf16 Bs[128 * 32];
    int tid = threadIdx.x, w = tid >> 6, L = tid & 63, quad = L >> 4, l16 = L & 15;
    int wr = w >> 1, wc = w & 1;
    long R0 = (long)blockIdx.y * 128;
    long C0 = (long)blockIdx.x * 128;

    // staging source coords: thread tid -> row tid/4 (within 64-row sweep), k-elem (tid&3)*8
    int srow = tid >> 2;
    int kcol = (tid & 3) * 8;
    const bf16* gA0 = A  + (R0 + srow) * 1024 + kcol;        // rows 0..63 of tile
    const bf16* gA1 = A  + (R0 + 64 + srow) * 1024 + kcol;   // rows 64..127
    const bf16* gB0 = Wt + (C0 + srow) * 1024 + kcol;
    const bf16* gB1 = Wt + (C0 + 64 + srow) * 1024 + kcol;
    // wave-uniform LDS bases: wave w owns bytes [w*1024, w*1024+1024) of each 4KB sweep
    char* sA = (char*)As + w * 1024;
    char* sB = (char*)Bs + w * 1024;

    // loop-invariant fragment pointers: As[row][k] row-major, 32 k-elems (64B) per row
    const s8v* fA[4];
    const s8v* fB[4];
    #pragma unroll
    for (int i = 0; i < 4; i++) fA[i] = (const s8v*)&As[(wr * 64 + i * 16 + l16) * 32 + quad * 8];
    #pragma unroll
    for (int jj = 0; jj < 4; jj++) fB[jj] = (const s8v*)&Bs[(wc * 64 + jj * 16 + l16) * 32 + quad * 8];

    f4v acc[4][4] = {};

    for (int kt = 0; kt < 32; ++kt) {
        async_copy16(gA0, sA);
        async_copy16(gA1, sA + 4096);
        async_copy16(gB0, sB);
        async_copy16(gB1, sB + 4096);
        gA0 += 32; gA1 += 32; gB0 += 32; gB1 += 32;
        __syncthreads();   // vmcnt(0) drain: LDS tile ready

        s8v av[4], bv[4];
        #pragma unroll
        for (int i = 0; i < 4; i++) av[i] = *fA[i];
        #pragma unroll
        for (int jj = 0; jj < 4; jj++) bv[jj] = *fB[jj];
        #pragma unroll
        for (int i = 0; i < 4; i++)
            #pragma unroll
            for (int jj = 0; jj < 4; jj++)
                acc[i][jj] = __builtin_amdgcn_mfma_f32_16x16x32_bf16(av[i], bv[jj], acc[i][jj], 0, 0, 0);

        __syncthreads();   // reads done before next stage overwrites
    }

    #pragma unroll
    for (int i = 0; i < 4; i++) {
        #pragma unroll
        for (int jj = 0; jj < 4; jj++) {
            #pragma unroll
            for (int p = 0; p < 4; p++) {
                long row = R0 + wr * 64 + i * 16 + quad * 4 + p;
                long col = C0 + wc * 64 + jj * 16 + l16;
                if (row < 8128 && col < VV)
                    out[row * VV + col] = acc[i][jj][p] + bias[col];
            }
        }
    }
}

// ---------------- per-row log-softmax loss ----------------
__global__ __launch_bounds__(256) void loss_kernel(
    const float* __restrict__ logits,
    const int* __restrict__ sent,
    float* __restrict__ rowloss)
{
    __shared__ float red[256];
    int r = blockIdx.x;
    int b = r / TM1, t = r % TM1;
    const float* row = logits + (long)r * VV;
    int tid = threadIdx.x;

    float mx = -INFINITY;
    for (int v = tid; v < VV; v += 256) mx = fmaxf(mx, row[v]);
    red[tid] = mx; __syncthreads();
    for (int s = 128; s > 0; s >>= 1) {
        if (tid < s) red[tid] = fmaxf(red[tid], red[tid + s]);
        __syncthreads();
    }
    mx = red[0];
    __syncthreads();

    float sum = 0.0f;
    for (int v = tid; v < VV; v += 256) sum += expf(row[v] - mx);
    red[tid] = sum; __syncthreads();
    for (int s = 128; s > 0; s >>= 1) {
        if (tid < s) red[tid] += red[tid + s];
        __syncthreads();
    }
    if (tid == 0) {
        int gt = sent[b * TT + t + 1];
        float val = 0.0f;
        if (gt != 0) val = -(row[gt] - mx - logf(red[0]));
        rowloss[r] = val;
    }
}

__global__ void final_kernel(const float* __restrict__ rowloss,
                             const int* __restrict__ length,
                             float* __restrict__ out0)
{
    int b = threadIdx.x;   // 0..63
    float s = 0.0f;
    for (int t = 0; t < TM1; t++) s += rowloss[b * TM1 + t];
    s /= (float)length[b];
    #pragma unroll
    for (int off = 32; off > 0; off >>= 1) s += __shfl_down(s, off, 64);
    if (b == 0) out0[0] = s;
}

extern "C" void kernel_launch(void* const* d_in, const int* in_sizes, int n_in,
                              void* d_out, int out_size, void* d_ws, size_t ws_size,
                              hipStream_t stream) {
    const int*   sent    = (const int*)d_in[0];
    const int*   length  = (const int*)d_in[1];
    const float* wordvec = (const float*)d_in[2];
    const float* w_ih0   = (const float*)d_in[3];
    const float* w_hh0   = (const float*)d_in[4];
    const float* b0      = (const float*)d_in[5];
    const float* w_ih1   = (const float*)d_in[6];
    const float* w_hh1   = (const float*)d_in[7];
    const float* b1      = (const float*)d_in[8];
    const float* w_out   = (const float*)d_in[9];
    const float* b_out   = (const float*)d_in[10];
    float* out = (float*)d_out;

    char* W = (char*)d_ws;
    size_t o = 0;
    bf16* X      = (bf16*)(W + o); o += 128L * 64 * 320 * 2;        // 5,242,880
    bf16* wtih0  = (bf16*)(W + o); o += 4096L * 320 * 2;            // 2,621,440
    bf16* wthh0  = (bf16*)(W + o); o += 4096L * 1024 * 2;           // 8,388,608
    bf16* wtih1  = (bf16*)(W + o); o += 4096L * 1024 * 2;
    bf16* wthh1  = (bf16*)(W + o); o += 4096L * 1024 * 2;
    bf16* woutt  = (bf16*)(W + o); o += 10112L * 1024 * 2;          // 20,709,376
    bf16* H1     = (bf16*)(W + o); o += 8192L * 1024 * 2;           // 16,777,216
    // zero region (contiguous): h0b0, h1b0, c0, c1
    bf16*  h0b0  = (bf16*)(W + o); o += 64L * 1024 * 2;
    bf16*  h1b0  = (bf16*)(W + o); o += 64L * 1024 * 2;
    float* c0    = (float*)(W + o); o += 64L * 1024 * 4;
    float* c1    = (float*)(W + o); o += 64L * 1024 * 4;
    bf16*  h0b1  = (bf16*)(W + o); o += 64L * 1024 * 2;
    bf16*  h1b1  = (bf16*)(W + o); o += 64L * 1024 * 2;
    float* rowloss = (float*)(W + o); o += 8128L * 4;

    // zero h0b0,h1b0,c0,c1 = 786432 B = 196608 floats
    zero_kernel<<<768, 256, 0, stream>>>((float*)h0b0, 196608);
    embed_kernel<<<128 * 64, 64, 0, stream>>>(sent, wordvec, X);
    transpose_bf16_kernel<<<dim3(128, 10), 256, 0, stream>>>(w_ih0, wtih0, 300, 4096, 320);
    transpose_bf16_kernel<<<dim3(128, 32), 256, 0, stream>>>(w_hh0, wthh0, 1024, 4096, 1024);
    transpose_bf16_kernel<<<dim3(128, 32), 256, 0, stream>>>(w_ih1, wtih1, 1024, 4096, 1024);
    transpose_bf16_kernel<<<dim3(128, 32), 256, 0, stream>>>(w_hh1, wthh1, 1024, 4096, 1024);
    transpose_bf16_kernel<<<dim3(316, 32), 256, 0, stream>>>(w_out, woutt, 1024, VV, 1024);

    // A-only: layer0 step 0 (h0_prev = zeros in h0b0) -> h0(0) in h0b1
    step_kernel<<<64, 1024, 0, stream>>>(
        X, 0, 0, 1,
        h0b0, h0b1, h1b0, h1b1,
        wtih0, wthh0, wtih1, wthh1, b0, b1, c0, c1, H1);

    // combo steps: B(t) uses h0(t), h1(t-1); A(t+1) uses x(t+1), h0(t)
    for (int t = 0; t < TM1; t++) {
        bf16* h0in  = (t & 1) ? h0b0 : h0b1;
        bf16* h0out = (t & 1) ? h0b1 : h0b0;
        bf16* h1in  = (t & 1) ? h1b1 : h1b0;
        bf16* h1out = (t & 1) ? h1b0 : h1b1;
        step_kernel<<<128, 1024, 0, stream>>>(
            X, t + 1, t, 0,
            h0in, h0out, h1in, h1out,
            wtih0, wthh0, wtih1, wthh1, b0, b1, c0, c1, H1);
    }

    out_gemm_mfma<<<dim3(79, 64), 256, 0, stream>>>(H1, woutt, b_out, out + 1);
    loss_kernel<<<TM1 * BB, 256, 0, stream>>>(out + 1, sent, rowloss);
    final_kernel<<<1, 64, 0, stream>>>(rowloss, length, out);
}